// Round 3
// baseline (163.211 us; speedup 1.0000x reference)
//
#include <hip/hip_runtime.h>
#include <hip/hip_bf16.h>

#define NB     8
#define CIN    14
#define COUT   128
#define HW     384
#define OUT_HW 131
#define P      (OUT_HW*OUT_HW)       // 17161
#define TOTPIX (NB*P)                // 137288
#define ROWS   390                   // 3 guard rows + 384 + 3 guard rows
#define NTOT   (NB*CIN*HW*HW)        // 16,515,072

typedef unsigned long long u64;
typedef unsigned int u32;

struct PackedW {
    uint4 w3p[COUT];      // per co: w3lo(lo32,hi32), w3hi(lo32,hi32)
    uint4 padz;           // z planes for conv3 zero-pad samples (i==0||j==0)
    uint4 ringz;          // z planes for conv2-pad ring pixels
    u64   w1pack[CIN];    // 49 sign bits per channel (bit 7*dy+dx)
    u32   w2e[COUT];      // low14: w2 sign bits; high16: t2 threshold (signed)
    int   t3[COUT];       // conv3 popcount threshold
    int   b1i[CIN];
};

// ---------------- K1: partial sums + last-block mean & weight packing ------
__global__ __launch_bounds__(256) void reduce_and_pack(
    const float4* __restrict__ x, int n4,
    double* __restrict__ part, u32* __restrict__ ctr, float* __restrict__ meanp,
    const float* __restrict__ w1, const float* __restrict__ b1,
    const float* __restrict__ w2, const float* __restrict__ b2,
    const float* __restrict__ w3, const float* __restrict__ b3,
    PackedW* __restrict__ pw)
{
    const int tid = threadIdx.x;
    const int lane = tid & 63, wv = tid >> 6;
    __shared__ double wsum[4];

    // ---- phase 1: deterministic partial sum ----
    double s = 0.0;
    int stride = gridDim.x * blockDim.x;
    for (int idx = blockIdx.x * blockDim.x + tid; idx < n4; idx += stride) {
        float4 v = x[idx];
        s += (double)v.x; s += (double)v.y; s += (double)v.z; s += (double)v.w;
    }
    for (int off = 32; off; off >>= 1) s += __shfl_down(s, off);
    if (lane == 0) wsum[wv] = s;
    __syncthreads();
    if (tid == 0) part[blockIdx.x] = ((wsum[0] + wsum[1]) + (wsum[2] + wsum[3]));

    // ---- last-block election ----
    __threadfence();
    __shared__ u32 amLast;
    if (tid == 0) amLast = (atomicAdd(ctr, 1u) == (u32)(gridDim.x - 1)) ? 1u : 0u;
    __syncthreads();
    if (!amLast) return;
    __threadfence();

    // ---- final mean (deterministic fixed-order tree) ----
    double t = 0.0;
    for (int i2 = tid; i2 < 1024; i2 += 256) t += ((const volatile double*)part)[i2];
    for (int off = 32; off; off >>= 1) t += __shfl_down(t, off);
    __syncthreads();
    if (lane == 0) wsum[wv] = t;
    __syncthreads();
    if (tid == 0)
        *meanp = (float)((((wsum[0] + wsum[1]) + (wsum[2] + wsum[3])) / (double)NTOT));

    // ---- weight packing ----
    __shared__ u64 sBorder[2];   // conv2 pad-frame y2 bits
    __shared__ u64 sPad[2];      // sign(round(b3)) ballots
    __shared__ u64 sRing[2];
    __shared__ u64 sw3lo[COUT], sw3hi[COUT];
    __shared__ int sb3[COUT];

    if (tid < COUT) {
        const float* wr = w3 + tid * COUT;
        u64 lo = 0, hi = 0;
        #pragma unroll 8
        for (int c = 0; c < 64; c++) lo |= (u64)(wr[c] >= 0.f) << c;
        #pragma unroll 8
        for (int c = 0; c < 64; c++) hi |= (u64)(wr[64 + c] >= 0.f) << c;
        pw->w3p[tid] = make_uint4((u32)lo, (u32)(lo >> 32), (u32)hi, (u32)(hi >> 32));
        sw3lo[tid] = lo; sw3hi[tid] = hi;

        u32 wb = 0;
        const float* w2r = w2 + tid * CIN;
        for (int c = 0; c < CIN; c++) wb |= (u32)(w2r[c] >= 0.f) << c;
        int b2i = (int)rintf(b2[tid]);
        int t2  = (CIN + b2i) >> 1;            // arithmetic floor
        pw->w2e[tid] = wb | ((u32)t2 << 16);

        int b3i = (int)rintf(b3[tid]);
        sb3[tid] = b3i;
        pw->t3[tid] = (COUT + b3i) >> 1;

        u64 bb2 = __ballot(b2i >= 0);
        u64 bb3 = __ballot(b3i >= 0);
        if (lane == 0) { sBorder[wv] = bb2; sPad[wv] = bb3; }
    } else {
        int q = tid - COUT;
        if (q < CIN) {
            const float* wr = w1 + q * 49;
            u64 pk = 0;
            for (int c = 0; c < 49; c++) pk |= (u64)(wr[c] >= 0.f) << c;
            pw->w1pack[q] = pk;
            pw->b1i[q] = (int)rintf(b1[q]);
        }
    }
    __syncthreads();

    if (tid < COUT) {
        int s3 = COUT + sb3[tid]
               - 2 * (int)(__popcll(sBorder[0] ^ sw3lo[tid]) + __popcll(sBorder[1] ^ sw3hi[tid]));
        u64 rb = __ballot(s3 >= 0);
        if (lane == 0) sRing[wv] = rb;
    }
    __syncthreads();
    if (tid == 0) {
        pw->padz  = make_uint4((u32)sPad[0],  (u32)(sPad[0] >> 32),  (u32)sPad[1],  (u32)(sPad[1] >> 32));
        pw->ringz = make_uint4((u32)sRing[0], (u32)(sRing[0] >> 32), (u32)sRing[1], (u32)(sRing[1] >> 32));
    }
}

// ---------------- K2: binarize + bit-pack into guarded layout --------------
// xbin[nc][rr][wp], rr in [0,390): guard rows 0..2 and 387..389 zero; wp in [0,8): 6,7 zero
__global__ __launch_bounds__(256) void pack_rows(
    const float* __restrict__ x, const float* __restrict__ meanp,
    u64* __restrict__ xbin)
{
    const float m = *meanp;
    const int lane = threadIdx.x & 63;
    int wid = (blockIdx.x * 256 + threadIdx.x) >> 6;
    const int nw = (gridDim.x * 256) >> 6;
    const int nrows = NB * CIN * ROWS;
    for (int row = wid; row < nrows; row += nw) {
        int nc = row / ROWS;
        int rr = row - nc * ROWS;
        int r  = rr - 3;
        u64 v = 0;
        if (r >= 0 && r < HW) {
            const float* xr = x + ((size_t)nc * HW + r) * HW;
            u64 b0 = __ballot(xr[lane]       >= m);
            u64 b1_ = __ballot(xr[64 + lane]  >= m);
            u64 b2_ = __ballot(xr[128 + lane] >= m);
            u64 b3_ = __ballot(xr[192 + lane] >= m);
            u64 b4_ = __ballot(xr[256 + lane] >= m);
            u64 b5_ = __ballot(xr[320 + lane] >= m);
            v = lane == 0 ? b0 : lane == 1 ? b1_ : lane == 2 ? b2_ :
                lane == 3 ? b3_ : lane == 4 ? b4_ : lane == 5 ? b5_ : 0;
        }
        if (lane < 8) xbin[(size_t)row * 8 + lane] = v;
    }
}

// ---------------- K3: per-pixel conv1+conv2+conv3 + direct stores ----------
__global__ __launch_bounds__(256) void bnn_out(
    const u64* __restrict__ xbin, const PackedW* __restrict__ pw,
    float* __restrict__ out)
{
    const int g = blockIdx.x * 256 + threadIdx.x;
    if (g >= TOTPIX) return;
    const u32 n   = (u32)g / P;
    const u32 pix = (u32)g - n * P;
    const u32 i   = pix / OUT_HW;
    const u32 j   = pix - i * OUT_HW;

    u32 z0, z1, z2, z3;
    if (i == 0 || j == 0) {
        uint4 t = pw->padz;  z0 = t.x; z1 = t.y; z2 = t.z; z3 = t.w;
    } else if (i == 1 || i == 130 || j == 1 || j == 130) {
        uint4 t = pw->ringz; z0 = t.x; z1 = t.y; z2 = t.z; z3 = t.w;
    } else {
        const int p0 = 3 * (int)i - 4;       // conv1 row center, in [2,383]
        const int c0 = 3 * (int)j - 7;       // leftmost input col, in [-1,380]
        const int lsh = (c0 < 0) ? 1 : 0;
        const int c0c = (c0 < 0) ? 0 : c0;
        const int k   = c0c >> 6;
        const int off = c0c & 63;
        const u64 selz = off ? ~0ull : 0ull;
        const int shl1 = (64 - off) & 63;
        u32 vm = 0x7Fu;
        if (c0 < 0)   vm = 0x7Eu;
        if (c0 == 380) vm = 0x0Fu;
        u64 vmrep = (u64)vm * 0x0000040810204081ull;   // replicate at stripes 0,7,...,42
        u64 rmask = (1ull << 49) - 1;
        if (p0 < 3)   rmask &= ~((1ull << (7 * (3 - p0))) - 1);
        if (p0 > 380) rmask &= (1ull << (7 * (387 - p0))) - 1;
        const u64 M = vmrep & rmask;
        const int npop = (int)__popcll(M);

        u32 y1v = 0;
        #pragma unroll
        for (int ci = 0; ci < CIN; ci++) {
            const u64* rb = xbin + (((size_t)n * CIN + ci) * ROWS + (u32)p0) * 8 + k;
            u64 bits = 0;
            #pragma unroll
            for (int dy = 0; dy < 7; dy++) {
                u64 w0 = rb[dy * 8];
                u64 w1 = rb[dy * 8 + 1];
                u64 v = (w0 >> off) | ((w1 & selz) << shl1);
                u32 b7 = ((u32)v << lsh) & 0x7Fu;
                bits |= (u64)b7 << (7 * dy);
            }
            int T = pw->b1i[ci] + npop - 2 * (int)__popcll((bits ^ pw->w1pack[ci]) & M);
            y1v |= (u32)(T >= 0) << ci;
        }

        // conv2: y2 = 128 bits
        u64 y2lo = 0, y2hi = 0;
        #pragma unroll
        for (int co = 0; co < 64; co++) {
            u32 e = pw->w2e[co];
            int p = __popc((y1v ^ e) & 0x3FFFu);
            y2lo |= (u64)(p <= ((int)e >> 16)) << co;
        }
        #pragma unroll
        for (int co = 0; co < 64; co++) {
            u32 e = pw->w2e[64 + co];
            int p = __popc((y1v ^ e) & 0x3FFFu);
            y2hi |= (u64)(p <= ((int)e >> 16)) << co;
        }

        // conv3: z = 128 bits
        z0 = z1 = z2 = z3 = 0;
        #pragma unroll
        for (int co = 0; co < 32; co++) {
            uint4 w = pw->w3p[co];
            int pp = (int)(__popcll(y2lo ^ (((u64)w.y << 32) | w.x))
                         + __popcll(y2hi ^ (((u64)w.w << 32) | w.z)));
            z0 |= (u32)(pp <= pw->t3[co]) << co;
        }
        #pragma unroll
        for (int co = 0; co < 32; co++) {
            uint4 w = pw->w3p[32 + co];
            int pp = (int)(__popcll(y2lo ^ (((u64)w.y << 32) | w.x))
                         + __popcll(y2hi ^ (((u64)w.w << 32) | w.z)));
            z1 |= (u32)(pp <= pw->t3[32 + co]) << co;
        }
        #pragma unroll
        for (int co = 0; co < 32; co++) {
            uint4 w = pw->w3p[64 + co];
            int pp = (int)(__popcll(y2lo ^ (((u64)w.y << 32) | w.x))
                         + __popcll(y2hi ^ (((u64)w.w << 32) | w.z)));
            z2 |= (u32)(pp <= pw->t3[64 + co]) << co;
        }
        #pragma unroll
        for (int co = 0; co < 32; co++) {
            uint4 w = pw->w3p[96 + co];
            int pp = (int)(__popcll(y2lo ^ (((u64)w.y << 32) | w.x))
                         + __popcll(y2hi ^ (((u64)w.w << 32) | w.z)));
            z3 |= (u32)(pp <= pw->t3[96 + co]) << co;
        }
    }

    // direct coalesced stores: out[((n*128+co)*P) + pix], lanes = consecutive pix
    float* op = out + (size_t)n * COUT * P + pix;
    #pragma unroll
    for (int co = 0; co < 128; co++) {
        u32 w = (co < 32) ? z0 : (co < 64) ? z1 : (co < 96) ? z2 : z3;
        float f = ((w >> (co & 31)) & 1u) ? 1.0f : -1.0f;
        __builtin_nontemporal_store(f, op + (size_t)co * P);
    }
}

extern "C" void kernel_launch(void* const* d_in, const int* in_sizes, int n_in,
                              void* d_out, int out_size, void* d_ws, size_t ws_size,
                              hipStream_t stream) {
    const float* x  = (const float*)d_in[0];
    const float* w1 = (const float*)d_in[1];
    const float* b1 = (const float*)d_in[2];
    const float* w2 = (const float*)d_in[3];
    const float* b2 = (const float*)d_in[4];
    const float* w3 = (const float*)d_in[5];
    const float* b3 = (const float*)d_in[6];
    float* out = (float*)d_out;

    // workspace layout
    double*  partials = (double*)d_ws;                        // 1024 * 8B
    u32*     ctr      = (u32*)((char*)d_ws + 8192);
    float*   meanp    = (float*)((char*)d_ws + 8256);
    PackedW* pw       = (PackedW*)((char*)d_ws + 8448);       // ~3.3 KB
    u64*     xbin     = (u64*)((char*)d_ws + 16384);          // 8*14*390*8*8B = 2.67 MB

    hipMemsetAsync(ctr, 0, sizeof(u32), stream);

    reduce_and_pack<<<1024, 256, 0, stream>>>((const float4*)x, NTOT / 4,
                                              partials, ctr, meanp,
                                              w1, b1, w2, b2, w3, b3, pw);
    pack_rows<<<1024, 256, 0, stream>>>(x, meanp, xbin);
    bnn_out<<<(TOTPIX + 255) / 256, 256, 0, stream>>>(xbin, pw, out);
}

// Round 4
// 96.837 us; speedup vs baseline: 1.6854x; 1.6854x over previous
//
#include <hip/hip_runtime.h>
#include <hip/hip_bf16.h>

#define NB     8
#define CIN    14
#define COUT   128
#define HW     384
#define OUT_HW 131
#define P      (OUT_HW*OUT_HW)       // 17161
#define TOTPIX (NB*P)                // 137288
#define ROWS   390                   // 3 guard rows + 384 + 3 guard rows
#define NTOT   (NB*CIN*HW*HW)        // 16,515,072

typedef unsigned long long u64;
typedef unsigned int u32;

struct PackedW {
    uint4 w3p[COUT];      // per co: w3lo(lo32,hi32), w3hi(lo32,hi32)
    uint4 padz;           // z planes for conv3 zero-pad samples (i==0||j==0)
    uint4 ringz;          // z planes for conv2-pad ring pixels
    u64   w1pack[CIN];    // 49 sign bits per channel (bit 7*dy+dx)
    u32   w2e[COUT];      // low14: w2 sign bits; high16: t2 threshold (signed)
    int   t3[COUT];       // conv3 popcount threshold
    int   b1i[CIN];
};

// ---------------- K1: per-block partial sums (deterministic, fence-free) ---
__global__ __launch_bounds__(256) void reduce_partial(
    const float4* __restrict__ x, double* __restrict__ part, int n4)
{
    double s0 = 0.0, s1 = 0.0;
    int stride = gridDim.x * blockDim.x;
    for (int idx = blockIdx.x * blockDim.x + threadIdx.x; idx < n4; idx += stride) {
        float4 v = x[idx];
        s0 += (double)v.x + (double)v.y;
        s1 += (double)v.z + (double)v.w;
    }
    double s = s0 + s1;
    for (int off = 32; off; off >>= 1) s += __shfl_down(s, off);
    __shared__ double wsum[4];
    int lane = threadIdx.x & 63, wv = threadIdx.x >> 6;
    if (lane == 0) wsum[wv] = s;
    __syncthreads();
    if (threadIdx.x == 0) part[blockIdx.x] = ((wsum[0] + wsum[1]) + (wsum[2] + wsum[3]));
}

// ---------------- K2: final mean + one-time weight packing (1 block) -------
__global__ __launch_bounds__(256) void finalize_pack(
    const double* __restrict__ part, float* __restrict__ meanp,
    const float* __restrict__ w1, const float* __restrict__ b1,
    const float* __restrict__ w2, const float* __restrict__ b2,
    const float* __restrict__ w3, const float* __restrict__ b3,
    PackedW* __restrict__ pw)
{
    const int tid = threadIdx.x;
    const int lane = tid & 63, wv = tid >> 6;
    __shared__ double wsum[4];

    // ---- deterministic mean ----
    double t = 0.0;
    for (int i2 = tid; i2 < 1024; i2 += 256) t += part[i2];
    for (int off = 32; off; off >>= 1) t += __shfl_down(t, off);
    if (lane == 0) wsum[wv] = t;
    __syncthreads();
    if (tid == 0)
        *meanp = (float)((((wsum[0] + wsum[1]) + (wsum[2] + wsum[3])) / (double)NTOT));

    // ---- weight packing ----
    __shared__ u64 sBorder[2];   // conv2 pad-frame y2 bits
    __shared__ u64 sPad[2];      // sign(round(b3)) ballots
    __shared__ u64 sRing[2];
    __shared__ u64 sw3lo[COUT], sw3hi[COUT];
    __shared__ int sb3[COUT];

    if (tid < COUT) {
        const float* wr = w3 + tid * COUT;
        u64 lo = 0, hi = 0;
        #pragma unroll 8
        for (int c = 0; c < 64; c++) lo |= (u64)(wr[c] >= 0.f) << c;
        #pragma unroll 8
        for (int c = 0; c < 64; c++) hi |= (u64)(wr[64 + c] >= 0.f) << c;
        pw->w3p[tid] = make_uint4((u32)lo, (u32)(lo >> 32), (u32)hi, (u32)(hi >> 32));
        sw3lo[tid] = lo; sw3hi[tid] = hi;

        u32 wb = 0;
        const float* w2r = w2 + tid * CIN;
        for (int c = 0; c < CIN; c++) wb |= (u32)(w2r[c] >= 0.f) << c;
        int b2i = (int)rintf(b2[tid]);
        int t2  = (CIN + b2i) >> 1;            // arithmetic floor
        pw->w2e[tid] = wb | ((u32)t2 << 16);

        int b3i = (int)rintf(b3[tid]);
        sb3[tid] = b3i;
        pw->t3[tid] = (COUT + b3i) >> 1;

        u64 bb2 = __ballot(b2i >= 0);
        u64 bb3 = __ballot(b3i >= 0);
        if (lane == 0) { sBorder[wv] = bb2; sPad[wv] = bb3; }
    } else {
        int q = tid - COUT;
        if (q < CIN) {
            const float* wr = w1 + q * 49;
            u64 pk = 0;
            for (int c = 0; c < 49; c++) pk |= (u64)(wr[c] >= 0.f) << c;
            pw->w1pack[q] = pk;
            pw->b1i[q] = (int)rintf(b1[q]);
        }
    }
    __syncthreads();

    if (tid < COUT) {
        int s3 = COUT + sb3[tid]
               - 2 * (int)(__popcll(sBorder[0] ^ sw3lo[tid]) + __popcll(sBorder[1] ^ sw3hi[tid]));
        u64 rb = __ballot(s3 >= 0);
        if (lane == 0) sRing[wv] = rb;
    }
    __syncthreads();
    if (tid == 0) {
        pw->padz  = make_uint4((u32)sPad[0],  (u32)(sPad[0] >> 32),  (u32)sPad[1],  (u32)(sPad[1] >> 32));
        pw->ringz = make_uint4((u32)sRing[0], (u32)(sRing[0] >> 32), (u32)sRing[1], (u32)(sRing[1] >> 32));
    }
}

// ---------------- K3: build 16384-entry conv2+conv3 LUT --------------------
// zlut[y1v] = 128 output sign bits (z0..z3)
__global__ __launch_bounds__(256) void zlut_build(
    const PackedW* __restrict__ pw, uint4* __restrict__ zlut)
{
    const u32 y1v = blockIdx.x * 256 + threadIdx.x;   // 64 blocks -> 16384

    u64 y2lo = 0, y2hi = 0;
    #pragma unroll 8
    for (int co = 0; co < 64; co++) {
        u32 e = pw->w2e[co];
        int p = __popc((y1v ^ e) & 0x3FFFu);
        y2lo |= (u64)(p <= ((int)e >> 16)) << co;
    }
    #pragma unroll 8
    for (int co = 0; co < 64; co++) {
        u32 e = pw->w2e[64 + co];
        int p = __popc((y1v ^ e) & 0x3FFFu);
        y2hi |= (u64)(p <= ((int)e >> 16)) << co;
    }

    u32 z[4] = {0, 0, 0, 0};
    #pragma unroll 4
    for (int co = 0; co < COUT; co++) {
        uint4 w = pw->w3p[co];
        int pp = (int)(__popcll(y2lo ^ (((u64)w.y << 32) | w.x))
                     + __popcll(y2hi ^ (((u64)w.w << 32) | w.z)));
        z[co >> 5] |= (u32)(pp <= pw->t3[co]) << (co & 31);
    }
    zlut[y1v] = make_uint4(z[0], z[1], z[2], z[3]);
}

// ---------------- K4: binarize + bit-pack into guarded layout --------------
// xbin[nc][rr][wp], rr in [0,390): guard rows 0..2 and 387..389 zero; wp in [0,8): 6,7 zero
__global__ __launch_bounds__(256) void pack_rows(
    const float* __restrict__ x, const float* __restrict__ meanp,
    u64* __restrict__ xbin)
{
    const float m = *meanp;
    const int lane = threadIdx.x & 63;
    int wid = (blockIdx.x * 256 + threadIdx.x) >> 6;
    const int nw = (gridDim.x * 256) >> 6;
    const int nrows = NB * CIN * ROWS;
    for (int row = wid; row < nrows; row += nw) {
        int nc = row / ROWS;
        int rr = row - nc * ROWS;
        int r  = rr - 3;
        u64 v = 0;
        if (r >= 0 && r < HW) {
            const float* xr = x + ((size_t)nc * HW + r) * HW;
            u64 b0 = __ballot(xr[lane]       >= m);
            u64 b1_ = __ballot(xr[64 + lane]  >= m);
            u64 b2_ = __ballot(xr[128 + lane] >= m);
            u64 b3_ = __ballot(xr[192 + lane] >= m);
            u64 b4_ = __ballot(xr[256 + lane] >= m);
            u64 b5_ = __ballot(xr[320 + lane] >= m);
            v = lane == 0 ? b0 : lane == 1 ? b1_ : lane == 2 ? b2_ :
                lane == 3 ? b3_ : lane == 4 ? b4_ : lane == 5 ? b5_ : 0;
        }
        if (lane < 8) xbin[(size_t)row * 8 + lane] = v;
    }
}

// ---------------- K5: per-pixel conv1 + LUT + direct stores ----------------
__global__ __launch_bounds__(256) void bnn_out(
    const u64* __restrict__ xbin, const PackedW* __restrict__ pw,
    const uint4* __restrict__ zlut, float* __restrict__ out)
{
    const int g = blockIdx.x * 256 + threadIdx.x;
    if (g >= TOTPIX) return;
    const u32 n   = (u32)g / P;
    const u32 pix = (u32)g - n * P;
    const u32 i   = pix / OUT_HW;
    const u32 j   = pix - i * OUT_HW;

    u32 z0, z1, z2, z3;
    if (i == 0 || j == 0) {
        uint4 t = pw->padz;  z0 = t.x; z1 = t.y; z2 = t.z; z3 = t.w;
    } else if (i == 1 || i == 130 || j == 1 || j == 130) {
        uint4 t = pw->ringz; z0 = t.x; z1 = t.y; z2 = t.z; z3 = t.w;
    } else {
        const int p0 = 3 * (int)i - 4;       // conv1 row center, in [2,383]
        const int c0 = 3 * (int)j - 7;       // leftmost input col, in [-1,380]
        const int lsh = (c0 < 0) ? 1 : 0;
        const int c0c = (c0 < 0) ? 0 : c0;
        const int k   = c0c >> 6;
        const int off = c0c & 63;
        const u64 selz = off ? ~0ull : 0ull;
        const int shl1 = (64 - off) & 63;
        u32 vm = 0x7Fu;
        if (c0 < 0)   vm = 0x7Eu;
        if (c0 == 380) vm = 0x0Fu;
        u64 vmrep = (u64)vm * 0x0000040810204081ull;   // replicate at stripes 0,7,...,42
        u64 rmask = (1ull << 49) - 1;
        if (p0 < 3)   rmask &= ~((1ull << (7 * (3 - p0))) - 1);
        if (p0 > 380) rmask &= (1ull << (7 * (387 - p0))) - 1;
        const u64 M = vmrep & rmask;
        const int npop = (int)__popcll(M);

        u32 y1v = 0;
        #pragma unroll
        for (int ci = 0; ci < CIN; ci++) {
            const u64* rb = xbin + (((size_t)n * CIN + ci) * ROWS + (u32)p0) * 8 + k;
            u64 bits = 0;
            #pragma unroll
            for (int dy = 0; dy < 7; dy++) {
                u64 w0 = rb[dy * 8];
                u64 w1 = rb[dy * 8 + 1];
                u64 v = (w0 >> off) | ((w1 & selz) << shl1);
                u32 b7 = ((u32)v << lsh) & 0x7Fu;
                bits |= (u64)b7 << (7 * dy);
            }
            int T = pw->b1i[ci] + npop - 2 * (int)__popcll((bits ^ pw->w1pack[ci]) & M);
            y1v |= (u32)(T >= 0) << ci;
        }

        uint4 zz = zlut[y1v];
        z0 = zz.x; z1 = zz.y; z2 = zz.z; z3 = zz.w;
    }

    // direct coalesced stores: out[((n*128+co)*P) + pix], lanes = consecutive pix
    float* op = out + (size_t)n * COUT * P + pix;
    #pragma unroll
    for (int co = 0; co < 128; co++) {
        u32 w = (co < 32) ? z0 : (co < 64) ? z1 : (co < 96) ? z2 : z3;
        float f = ((w >> (co & 31)) & 1u) ? 1.0f : -1.0f;
        __builtin_nontemporal_store(f, op + (size_t)co * P);
    }
}

extern "C" void kernel_launch(void* const* d_in, const int* in_sizes, int n_in,
                              void* d_out, int out_size, void* d_ws, size_t ws_size,
                              hipStream_t stream) {
    const float* x  = (const float*)d_in[0];
    const float* w1 = (const float*)d_in[1];
    const float* b1 = (const float*)d_in[2];
    const float* w2 = (const float*)d_in[3];
    const float* b2 = (const float*)d_in[4];
    const float* w3 = (const float*)d_in[5];
    const float* b3 = (const float*)d_in[6];
    float* out = (float*)d_out;

    // workspace layout
    double*  partials = (double*)d_ws;                        // 1024 * 8B
    float*   meanp    = (float*)((char*)d_ws + 8192);
    PackedW* pw       = (PackedW*)((char*)d_ws + 8448);       // ~3.3 KB
    uint4*   zlut     = (uint4*)((char*)d_ws + 16384);        // 16384*16B = 256 KB
    u64*     xbin     = (u64*)((char*)d_ws + 16384 + 262144); // 2.67 MB

    reduce_partial<<<1024, 256, 0, stream>>>((const float4*)x, partials, NTOT / 4);
    finalize_pack<<<1, 256, 0, stream>>>(partials, meanp, w1, b1, w2, b2, w3, b3, pw);
    zlut_build<<<64, 256, 0, stream>>>(pw, zlut);
    pack_rows<<<1024, 256, 0, stream>>>(x, meanp, xbin);
    bnn_out<<<(TOTPIX + 255) / 256, 256, 0, stream>>>(xbin, pw, zlut, out);
}

// Round 5
// 83.923 us; speedup vs baseline: 1.9448x; 1.1539x over previous
//
#include <hip/hip_runtime.h>
#include <hip/hip_bf16.h>

#define NB     8
#define CIN    14
#define COUT   128
#define HW     384
#define OUT_HW 131
#define P      (OUT_HW*OUT_HW)       // 17161
#define TOTPIX (NB*P)                // 137288
#define ROWS   390                   // 3 guard rows + 384 + 3 guard rows
#define NTOT   (NB*CIN*HW*HW)        // 16,515,072
#define WPP    68                    // waves per (n,co) plane in unpack (68*256 >= P)

typedef unsigned long long u64;
typedef unsigned int u32;

struct PackedW {
    uint4 w3p[COUT];      // per co: w3lo(lo32,hi32), w3hi(lo32,hi32)
    uint4 padz;           // z planes for conv3 zero-pad samples (i==0||j==0)
    uint4 ringz;          // z planes for conv2-pad ring pixels
    u64   w1pack[CIN];    // 49 sign bits per channel (bit 7*dy+dx)
    u32   w2e[COUT];      // low14: w2 sign bits; high16: t2 threshold (signed)
    int   t3[COUT];       // conv3 popcount threshold
    int   b1i[CIN];
};

// ---------------- K1: per-block partial sums (deterministic, fence-free) ---
__global__ __launch_bounds__(256) void reduce_partial(
    const float4* __restrict__ x, double* __restrict__ part, int n4)
{
    double s0 = 0.0, s1 = 0.0;
    int stride = gridDim.x * blockDim.x;
    for (int idx = blockIdx.x * blockDim.x + threadIdx.x; idx < n4; idx += stride) {
        float4 v = x[idx];
        s0 += (double)v.x + (double)v.y;
        s1 += (double)v.z + (double)v.w;
    }
    double s = s0 + s1;
    for (int off = 32; off; off >>= 1) s += __shfl_down(s, off);
    __shared__ double wsum[4];
    int lane = threadIdx.x & 63, wv = threadIdx.x >> 6;
    if (lane == 0) wsum[wv] = s;
    __syncthreads();
    if (threadIdx.x == 0) part[blockIdx.x] = ((wsum[0] + wsum[1]) + (wsum[2] + wsum[3]));
}

// ---------------- K2: final mean + one-time weight packing (1 block) -------
__global__ __launch_bounds__(256) void finalize_pack(
    const double* __restrict__ part, float* __restrict__ meanp,
    const float* __restrict__ w1, const float* __restrict__ b1,
    const float* __restrict__ w2, const float* __restrict__ b2,
    const float* __restrict__ w3, const float* __restrict__ b3,
    PackedW* __restrict__ pw)
{
    const int tid = threadIdx.x;
    const int lane = tid & 63, wv = tid >> 6;
    __shared__ double wsum[4];

    // ---- deterministic mean ----
    double t = 0.0;
    for (int i2 = tid; i2 < 1024; i2 += 256) t += part[i2];
    for (int off = 32; off; off >>= 1) t += __shfl_down(t, off);
    if (lane == 0) wsum[wv] = t;
    __syncthreads();
    if (tid == 0)
        *meanp = (float)((((wsum[0] + wsum[1]) + (wsum[2] + wsum[3])) / (double)NTOT));

    // ---- weight packing ----
    __shared__ u64 sBorder[2];   // conv2 pad-frame y2 bits
    __shared__ u64 sPad[2];      // sign(round(b3)) ballots
    __shared__ u64 sRing[2];
    __shared__ u64 sw3lo[COUT], sw3hi[COUT];
    __shared__ int sb3[COUT];

    if (tid < COUT) {
        const float* wr = w3 + tid * COUT;
        u64 lo = 0, hi = 0;
        #pragma unroll 8
        for (int c = 0; c < 64; c++) lo |= (u64)(wr[c] >= 0.f) << c;
        #pragma unroll 8
        for (int c = 0; c < 64; c++) hi |= (u64)(wr[64 + c] >= 0.f) << c;
        pw->w3p[tid] = make_uint4((u32)lo, (u32)(lo >> 32), (u32)hi, (u32)(hi >> 32));
        sw3lo[tid] = lo; sw3hi[tid] = hi;

        u32 wb = 0;
        const float* w2r = w2 + tid * CIN;
        for (int c = 0; c < CIN; c++) wb |= (u32)(w2r[c] >= 0.f) << c;
        int b2i = (int)rintf(b2[tid]);
        int t2  = (CIN + b2i) >> 1;            // arithmetic floor
        pw->w2e[tid] = wb | ((u32)t2 << 16);

        int b3i = (int)rintf(b3[tid]);
        sb3[tid] = b3i;
        pw->t3[tid] = (COUT + b3i) >> 1;

        u64 bb2 = __ballot(b2i >= 0);
        u64 bb3 = __ballot(b3i >= 0);
        if (lane == 0) { sBorder[wv] = bb2; sPad[wv] = bb3; }
    } else {
        int q = tid - COUT;
        if (q < CIN) {
            const float* wr = w1 + q * 49;
            u64 pk = 0;
            for (int c = 0; c < 49; c++) pk |= (u64)(wr[c] >= 0.f) << c;
            pw->w1pack[q] = pk;
            pw->b1i[q] = (int)rintf(b1[q]);
        }
    }
    __syncthreads();

    if (tid < COUT) {
        int s3 = COUT + sb3[tid]
               - 2 * (int)(__popcll(sBorder[0] ^ sw3lo[tid]) + __popcll(sBorder[1] ^ sw3hi[tid]));
        u64 rb = __ballot(s3 >= 0);
        if (lane == 0) sRing[wv] = rb;
    }
    __syncthreads();
    if (tid == 0) {
        pw->padz  = make_uint4((u32)sPad[0],  (u32)(sPad[0] >> 32),  (u32)sPad[1],  (u32)(sPad[1] >> 32));
        pw->ringz = make_uint4((u32)sRing[0], (u32)(sRing[0] >> 32), (u32)sRing[1], (u32)(sRing[1] >> 32));
    }
}

// ---------------- K3: pack rows + build zlut (merged) ----------------------
// blocks 0..1023: binarize+pack x into guarded layout
// blocks 1024..1087: zlut[y1v] = 128 output sign bits
__global__ __launch_bounds__(256) void pack_and_zlut(
    const float* __restrict__ x, const float* __restrict__ meanp,
    u64* __restrict__ xbin, const PackedW* __restrict__ pw,
    uint4* __restrict__ zlut)
{
    if (blockIdx.x >= 1024) {
        const u32 y1v = (blockIdx.x - 1024) * 256 + threadIdx.x;   // 16384 entries
        u64 y2lo = 0, y2hi = 0;
        #pragma unroll 8
        for (int co = 0; co < 64; co++) {
            u32 e = pw->w2e[co];
            int p = __popc((y1v ^ e) & 0x3FFFu);
            y2lo |= (u64)(p <= ((int)e >> 16)) << co;
        }
        #pragma unroll 8
        for (int co = 0; co < 64; co++) {
            u32 e = pw->w2e[64 + co];
            int p = __popc((y1v ^ e) & 0x3FFFu);
            y2hi |= (u64)(p <= ((int)e >> 16)) << co;
        }
        u32 z[4] = {0, 0, 0, 0};
        #pragma unroll 4
        for (int co = 0; co < COUT; co++) {
            uint4 w = pw->w3p[co];
            int pp = (int)(__popcll(y2lo ^ (((u64)w.y << 32) | w.x))
                         + __popcll(y2hi ^ (((u64)w.w << 32) | w.z)));
            z[co >> 5] |= (u32)(pp <= pw->t3[co]) << (co & 31);
        }
        zlut[y1v] = make_uint4(z[0], z[1], z[2], z[3]);
        return;
    }

    const float m = *meanp;
    const int lane = threadIdx.x & 63;
    int wid = (blockIdx.x * 256 + threadIdx.x) >> 6;
    const int nw = (1024 * 256) >> 6;
    const int nrows = NB * CIN * ROWS;
    for (int row = wid; row < nrows; row += nw) {
        int nc = row / ROWS;
        int rr = row - nc * ROWS;
        int r  = rr - 3;
        u64 v = 0;
        if (r >= 0 && r < HW) {
            const float* xr = x + ((size_t)nc * HW + r) * HW;
            u64 b0 = __ballot(xr[lane]       >= m);
            u64 b1_ = __ballot(xr[64 + lane]  >= m);
            u64 b2_ = __ballot(xr[128 + lane] >= m);
            u64 b3_ = __ballot(xr[192 + lane] >= m);
            u64 b4_ = __ballot(xr[256 + lane] >= m);
            u64 b5_ = __ballot(xr[320 + lane] >= m);
            v = lane == 0 ? b0 : lane == 1 ? b1_ : lane == 2 ? b2_ :
                lane == 3 ? b3_ : lane == 4 ? b4_ : lane == 5 ? b5_ : 0;
        }
        if (lane < 8) xbin[(size_t)row * 8 + lane] = v;
    }
}

// ---------------- K4: per-pixel conv1 + LUT -> packed z planes -------------
// zws layout: 4 planes of TOTPIX u32: zws[q*TOTPIX + n*P + pix]
__global__ __launch_bounds__(256) void conv_z(
    const u64* __restrict__ xbin, const PackedW* __restrict__ pw,
    const uint4* __restrict__ zlut, u32* __restrict__ zws)
{
    const int g = blockIdx.x * 256 + threadIdx.x;
    if (g >= TOTPIX) return;
    const u32 n   = (u32)g / P;
    const u32 pix = (u32)g - n * P;
    const u32 i   = pix / OUT_HW;
    const u32 j   = pix - i * OUT_HW;

    u32 z0, z1, z2, z3;
    if (i == 0 || j == 0) {
        uint4 t = pw->padz;  z0 = t.x; z1 = t.y; z2 = t.z; z3 = t.w;
    } else if (i == 1 || i == 130 || j == 1 || j == 130) {
        uint4 t = pw->ringz; z0 = t.x; z1 = t.y; z2 = t.z; z3 = t.w;
    } else {
        const int p0 = 3 * (int)i - 4;       // conv1 row center, in [2,383]
        const int c0 = 3 * (int)j - 7;       // leftmost input col, in [-1,380]
        const int lsh = (c0 < 0) ? 1 : 0;
        const int c0c = (c0 < 0) ? 0 : c0;
        const int k   = c0c >> 6;
        const int off = c0c & 63;
        const u64 selz = off ? ~0ull : 0ull;
        const int shl1 = (64 - off) & 63;
        u32 vm = 0x7Fu;
        if (c0 < 0)   vm = 0x7Eu;
        if (c0 == 380) vm = 0x0Fu;
        u64 vmrep = (u64)vm * 0x0000040810204081ull;   // replicate at stripes 0,7,...,42
        u64 rmask = (1ull << 49) - 1;
        if (p0 < 3)   rmask &= ~((1ull << (7 * (3 - p0))) - 1);
        if (p0 > 380) rmask &= (1ull << (7 * (387 - p0))) - 1;
        const u64 M = vmrep & rmask;
        const int npop = (int)__popcll(M);

        u32 y1v = 0;
        #pragma unroll
        for (int ci = 0; ci < CIN; ci++) {
            const u64* rb = xbin + (((size_t)n * CIN + ci) * ROWS + (u32)p0) * 8 + k;
            u64 bits = 0;
            #pragma unroll
            for (int dy = 0; dy < 7; dy++) {
                u64 w0 = rb[dy * 8];
                u64 w1 = rb[dy * 8 + 1];
                u64 v = (w0 >> off) | ((w1 & selz) << shl1);
                u32 b7 = ((u32)v << lsh) & 0x7Fu;
                bits |= (u64)b7 << (7 * dy);
            }
            int T = pw->b1i[ci] + npop - 2 * (int)__popcll((bits ^ pw->w1pack[ci]) & M);
            y1v |= (u32)(T >= 0) << ci;
        }

        uint4 zz = zlut[y1v];
        z0 = zz.x; z1 = zz.y; z2 = zz.z; z3 = zz.w;
    }

    zws[g]              = z0;
    zws[TOTPIX + g]     = z1;
    zws[2 * TOTPIX + g] = z2;
    zws[3 * TOTPIX + g] = z3;
}

// ---------------- K5: unpack bits -> +-1 floats, write-saturating ----------
// one wave handles 256 consecutive pixels of one (n,co) plane
__global__ __launch_bounds__(256) void unpack_out(
    const u32* __restrict__ zws, float* __restrict__ out)
{
    const int gid  = blockIdx.x * 256 + threadIdx.x;
    const int lane = threadIdx.x & 63;
    const u32 wid  = (u32)gid >> 6;          // global wave id
    const u32 plane = wid / WPP;             // n*128 + co
    if (plane >= NB * COUT) return;
    const u32 wseg = wid - plane * WPP;
    const u32 n  = plane >> 7;
    const u32 co = plane & 127u;
    const u32 b  = co & 31u;
    const u32* zp = zws + (co >> 5) * TOTPIX + n * P;
    float* op = out + (size_t)plane * P;
    int pix = wseg * 256 + lane;
    #pragma unroll
    for (int k = 0; k < 4; k++, pix += 64) {
        if (pix < P) {
            u32 w = zp[pix];
            float f = ((w >> b) & 1u) ? 1.0f : -1.0f;
            __builtin_nontemporal_store(f, op + pix);
        }
    }
}

extern "C" void kernel_launch(void* const* d_in, const int* in_sizes, int n_in,
                              void* d_out, int out_size, void* d_ws, size_t ws_size,
                              hipStream_t stream) {
    const float* x  = (const float*)d_in[0];
    const float* w1 = (const float*)d_in[1];
    const float* b1 = (const float*)d_in[2];
    const float* w2 = (const float*)d_in[3];
    const float* b2 = (const float*)d_in[4];
    const float* w3 = (const float*)d_in[5];
    const float* b3 = (const float*)d_in[6];
    float* out = (float*)d_out;

    // workspace layout
    double*  partials = (double*)d_ws;                         // 1024 * 8B
    float*   meanp    = (float*)((char*)d_ws + 8192);
    PackedW* pw       = (PackedW*)((char*)d_ws + 8448);        // ~3.3 KB
    uint4*   zlut     = (uint4*)((char*)d_ws + 16384);         // 256 KB
    u64*     xbin     = (u64*)((char*)d_ws + 16384 + 262144);  // 2.67 MB
    u32*     zws      = (u32*)((char*)d_ws + 16384 + 262144 + 2795520); // 2.2 MB

    reduce_partial<<<1024, 256, 0, stream>>>((const float4*)x, partials, NTOT / 4);
    finalize_pack<<<1, 256, 0, stream>>>(partials, meanp, w1, b1, w2, b2, w3, b3, pw);
    pack_and_zlut<<<1088, 256, 0, stream>>>(x, meanp, xbin, pw, zlut);
    conv_z<<<(TOTPIX + 255) / 256, 256, 0, stream>>>(xbin, pw, zlut, zws);
    unpack_out<<<(NB * COUT * WPP) / 4, 256, 0, stream>>>(zws, out);
}